// Round 2
// 366.102 us; speedup vs baseline: 1.0814x; 1.0814x over previous
//
#include <hip/hip_runtime.h>

// AfmoeAttention on MI355X (gfx950), round 8.
// r7 (144KB triple-buffer GEMM core) never ran: container failed twice.
// Prime suspect is the unproven 144KB static LDS (template precedent = 128KB).
// r8 = r7 with the pipelined core reshaped to exactly 128KB:
//   A double-buffered (2 x 16KB, staged 1 tile ahead)
//   B triple-buffered (3 x 32KB, staged 2 tiles ahead)
//   end-of-iter gate s_waitcnt vmcnt(4)  (B(t+1)+A(t+1) landed,
//   B(t+2)'s 4 loads stay in flight across the barrier; never vmcnt(0)
//   in the main loop)
// plus sched_barrier(0) after each lgkmcnt(0) (rule-18 insurance).
// Epilogues, attn, cvt_all unchanged from r6/r7.

#define LOG2E 1.44269504088896340736f

typedef __attribute__((ext_vector_type(4))) float f32x4;
typedef __attribute__((ext_vector_type(8))) short bf16x8;   // 8 x bf16 (4 VGPRs)

__device__ __forceinline__ float bf2f(unsigned short u) {
  union { unsigned u; float f; } x; x.u = ((unsigned)u) << 16; return x.f;
}
__device__ __forceinline__ unsigned short f2bf(float f) {
  union { float f; unsigned u; } x; x.f = f;
  unsigned r = x.u + 0x7fffu + ((x.u >> 16) & 1u);   // RNE
  return (unsigned short)(r >> 16);
}

// async global->LDS, 16B per lane. LDS dest = wave-uniform base + lane*16.
__device__ __forceinline__ void async16(void* lds, const void* g) {
  __builtin_amdgcn_global_load_lds(
      (const __attribute__((address_space(1))) unsigned*)g,
      (__attribute__((address_space(3))) unsigned*)lds, 16, 0, 0);
}
__device__ __forceinline__ void lds_fence() {
  __asm__ volatile("s_waitcnt lgkmcnt(0)" ::: "memory");
}

// ---------------------------------------------------------- fused cvt kernel
__global__ __launch_bounds__(256) void cvt_all(
    const float* __restrict__ s0, const float* __restrict__ s1,
    const float* __restrict__ s2, const float* __restrict__ s3,
    const float* __restrict__ s4, const float* __restrict__ s5,
    unsigned short* __restrict__ d0, unsigned short* __restrict__ d1,
    unsigned short* __restrict__ d2, unsigned short* __restrict__ d3,
    unsigned short* __restrict__ d4, unsigned short* __restrict__ d5) {
  long i = (long)blockIdx.x * 256 + threadIdx.x;   // f4 index
  const float* s; unsigned short* d; long off;
  if      (i < 2097152) { s = s0; d = d0; off = 0; }
  else if (i < 3145728) { s = s1; d = d1; off = 2097152; }
  else if (i < 3276800) { s = s2; d = d2; off = 3145728; }
  else if (i < 3407872) { s = s3; d = d3; off = 3276800; }
  else if (i < 4456448) { s = s4; d = d4; off = 3407872; }
  else                  { s = s5; d = d5; off = 4456448; }
  long j = i - off;
  float4 v = reinterpret_cast<const float4*>(s)[j];
  ushort4 u;
  u.x = f2bf(v.x); u.y = f2bf(v.y); u.z = f2bf(v.z); u.w = f2bf(v.w);
  reinterpret_cast<ushort4*>(d)[j] = u;
}

// ------------------------------------------- pipelined 128x256 GEMM core
// acc[4][4] = A[m0:m0+128, :2048] @ W[n0:n0+256, :2048]^T (per-wave 64x64).
// LDS row r = 64 bf16 = 8 x 16B chunks; logical chunk c stored at phys
// c ^ (r & 7). Staging pre-swizzles the GLOBAL source chunk so the linear
// global_load_lds dest yields that layout; frag reads apply the same XOR.
// LDS map (elements): A0 @ 0, A1 @ 8192, B0 @ 16384, B1 @ 32768, B2 @ 49152
//   (2 x 16KB A bufs + 3 x 32KB B bufs = 128KB exactly).
// Iter t: computes tile t from A[t&1], B[t%3];
//   phase0 stages A(t+1) (2 loads), phase1 stages B(t+2) (4 loads).
// Gate at end of iter t: vmcnt(4) -> A(t+1),B(t+1) landed, B(t+2) in flight.
__device__ __forceinline__ void gemm_main_big(
    const unsigned short* __restrict__ A, const unsigned short* __restrict__ W,
    int m0, int n0, unsigned short* lds, f32x4 acc[4][4]) {
  const int tid = threadIdx.x;
  const int w = tid >> 6, l = tid & 63, quad = l >> 4, l16 = l & 15;
  const int l7 = l16 & 7;
  const int wm = (w & 1) * 64, wn = (w >> 1) * 64;
  const int rlo = tid >> 3, ch = tid & 7;           // stage: row-low, chunk

  const f32x4 Z4 = {0.f, 0.f, 0.f, 0.f};
#pragma unroll
  for (int i = 0; i < 4; i++)
#pragma unroll
    for (int j = 0; j < 4; j++) acc[i][j] = Z4;

  // staging sources (pre-swizzled chunk); rows rlo, rlo+64(,+128,+192) share
  // rlo&7 so one swizzled source pointer serves all row-passes.
  const unsigned short* gA = A + (size_t)(m0 + rlo) * 2048 + ((ch ^ (rlo & 7)) * 8);
  const unsigned short* gB = W + (size_t)(n0 + rlo) * 2048 + ((ch ^ (rlo & 7)) * 8);

  // fragment read offsets (elements)
  int arow[4], brow[4];
#pragma unroll
  for (int mt = 0; mt < 4; mt++) arow[mt] = (wm + mt * 16 + l16) * 64;
#pragma unroll
  for (int nt = 0; nt < 4; nt++) brow[nt] = (wn + nt * 16 + l16) * 64;
  const int x0 = (quad ^ l7) * 8;          // k-slice 0: logical chunks 0..3
  const int x1 = ((4 + quad) ^ l7) * 8;    // k-slice 1: logical chunks 4..7

  unsigned short* const bA = lds;          // 2 x 8192 elems
  unsigned short* const bB = lds + 16384;  // 3 x 16384 elems

  // ---- prologue: A(0)->A0, B(0)->B0, B(1)->B1   (10 loads/thread)
  async16(bA + tid * 8,          gA);
  async16(bA + 4096 + tid * 8,   gA + 131072);
  async16(bB + tid * 8,          gB);
  async16(bB + 4096 + tid * 8,   gB + 131072);
  async16(bB + 8192 + tid * 8,   gB + 262144);
  async16(bB + 12288 + tid * 8,  gB + 393216);
  async16(bB + 16384 + tid * 8,  gB + 64);
  async16(bB + 20480 + tid * 8,  gB + 131072 + 64);
  async16(bB + 24576 + tid * 8,  gB + 262144 + 64);
  async16(bB + 28672 + tid * 8,  gB + 393216 + 64);
  __asm__ volatile("s_waitcnt vmcnt(4)" ::: "memory");   // A(0)+B(0) landed
  __builtin_amdgcn_s_barrier();

  int cb = 0;                               // B buffer index for tile t
  for (int t = 0; t < 32; ++t) {
    unsigned short* cbA = bA + (t & 1) * 8192;
    unsigned short* cbB = bB + cb * 16384;

    // -------- phase 0: stage A(t+1) || read k-slice0 || MFMA
    if (t < 31) {
      unsigned short* nA = bA + ((t + 1) & 1) * 8192;
      const int ko = (t + 1) * 64;
      async16(nA + tid * 8,        gA + ko);
      async16(nA + 4096 + tid * 8, gA + 131072 + ko);
    }
    bf16x8 a0[4], b0[4];
#pragma unroll
    for (int mt = 0; mt < 4; mt++)
      a0[mt] = *(const bf16x8*)&cbA[arow[mt] + x0];
#pragma unroll
    for (int nt = 0; nt < 4; nt++)
      b0[nt] = *(const bf16x8*)&cbB[brow[nt] + x0];
    __builtin_amdgcn_s_barrier();
    __asm__ volatile("s_waitcnt lgkmcnt(0)" ::: "memory");
    __builtin_amdgcn_sched_barrier(0);
    __builtin_amdgcn_s_setprio(1);
#pragma unroll
    for (int mt = 0; mt < 4; mt++)
#pragma unroll
      for (int nt = 0; nt < 4; nt++)
        acc[mt][nt] = __builtin_amdgcn_mfma_f32_16x16x32_bf16(
            a0[mt], b0[nt], acc[mt][nt], 0, 0, 0);
    __builtin_amdgcn_s_setprio(0);
    __builtin_amdgcn_s_barrier();

    // -------- phase 1: stage B(t+2) || read k-slice1 || MFMA || gate
    if (t < 30) {
      int nb = cb + 2; if (nb >= 3) nb -= 3;
      unsigned short* nB = bB + nb * 16384;
      const int ko = (t + 2) * 64;
      async16(nB + tid * 8,         gB + ko);
      async16(nB + 4096 + tid * 8,  gB + 131072 + ko);
      async16(nB + 8192 + tid * 8,  gB + 262144 + ko);
      async16(nB + 12288 + tid * 8, gB + 393216 + ko);
    }
    bf16x8 a1[4], b1[4];
#pragma unroll
    for (int mt = 0; mt < 4; mt++)
      a1[mt] = *(const bf16x8*)&cbA[arow[mt] + x1];
#pragma unroll
    for (int nt = 0; nt < 4; nt++)
      b1[nt] = *(const bf16x8*)&cbB[brow[nt] + x1];
    __builtin_amdgcn_s_barrier();
    __asm__ volatile("s_waitcnt lgkmcnt(0)" ::: "memory");
    __builtin_amdgcn_sched_barrier(0);
    __builtin_amdgcn_s_setprio(1);
#pragma unroll
    for (int mt = 0; mt < 4; mt++)
#pragma unroll
      for (int nt = 0; nt < 4; nt++)
        acc[mt][nt] = __builtin_amdgcn_mfma_f32_16x16x32_bf16(
            a1[mt], b1[nt], acc[mt][nt], 0, 0, 0);
    __builtin_amdgcn_s_setprio(0);
    if (t < 30) {
      __asm__ volatile("s_waitcnt vmcnt(4)" ::: "memory");  // t+1 landed
    } else if (t == 30) {
      __asm__ volatile("s_waitcnt vmcnt(0)" ::: "memory");  // tail drain (once)
    }
    __builtin_amdgcn_s_barrier();
    cb++; if (cb == 3) cb = 0;
  }
}

// --------------------------------------- fused QKVG GEMM + RMSNorm/RoPE/T
// N-space = [Q 2048 | K 256 | V 256 | G 2048] in 256-col tiles (ny 0..17).
// ny 0..7 : Q -> RMSNorm+RoPE, scale 1/8, write Qn[b][h][s][d]
// ny == 8 : K -> RMSNorm+RoPE, scale LOG2E, write Kn[b][kv][s][d]
// ny == 9 : V -> transpose-scatter to Vt[b][kv][d][s]
// ny 10..17: G -> plain bf16 store to gate[token][2048]
__global__ __launch_bounds__(512, 2) void gemm_qkvg(
    const unsigned short* __restrict__ X,
    const unsigned short* __restrict__ Wq, const unsigned short* __restrict__ Wk,
    const unsigned short* __restrict__ Wv, const unsigned short* __restrict__ Wg,
    const float* __restrict__ cosb, const float* __restrict__ sinb,
    const float* __restrict__ qg, const float* __restrict__ kg,
    unsigned short* __restrict__ Qn, unsigned short* __restrict__ Kn,
    unsigned short* __restrict__ Vt, unsigned short* __restrict__ gate) {
  __shared__ __attribute__((aligned(16))) unsigned short lds[65536];  // 128 KB
  const int ny = blockIdx.y;
  const unsigned short* W; int n0, type;
  if (ny < 8)       { W = Wq; n0 = ny * 256;        type = 0; }
  else if (ny == 8) { W = Wk; n0 = 0;               type = 1; }
  else if (ny == 9) { W = Wv; n0 = 0;               type = 2; }
  else              { W = Wg; n0 = (ny - 10) * 256; type = 3; }
  const int m0 = blockIdx.x * 128;

  f32x4 acc[4][4];
  gemm_main_big(X, W, m0, n0, lds, acc);

  const int tid = threadIdx.x;
  const int w = tid >> 6, l = tid & 63, quad = l >> 4, l16 = l & 15;
  const int wm = (w & 1) * 64, wn = (w >> 1) * 64;

  if (type == 3) {          // gate: plain bf16 store
#pragma unroll
    for (int mt = 0; mt < 4; mt++)
#pragma unroll
      for (int r = 0; r < 4; r++) {
        int row = m0 + wm + mt * 16 + quad * 4 + r;
#pragma unroll
        for (int nt = 0; nt < 4; nt++)
          gate[(size_t)row * 2048 + n0 + wn + nt * 16 + l16] =
              f2bf(acc[mt][nt][r]);
      }
    return;
  }
  if (type == 2) {          // V: transpose-scatter to Vt[b][kv][d][s]
#pragma unroll
    for (int mt = 0; mt < 4; mt++)
#pragma unroll
      for (int r = 0; r < 4; r++) {
        int row = m0 + wm + mt * 16 + quad * 4 + r;
        int b = row >> 11, s = row & 2047;
#pragma unroll
        for (int nt = 0; nt < 4; nt++) {
          int col = wn + nt * 16 + l16;
          int kvh = col >> 6, d = col & 63;
          Vt[((size_t)(b * 4 + kvh) * 64 + d) * 2048 + s] =
              f2bf(acc[mt][nt][r]);
        }
      }
    return;
  }

  // Q/K: RMSNorm (f32 acc) + RoPE + scale, transposed store
  const float* gamma = (type == 0) ? qg : kg;
  const float scale  = (type == 0) ? 0.125f : LOG2E;
  const int hb = (n0 + wn) >> 6;     // head index for this wave's 64-col span
  float gv[4];
#pragma unroll
  for (int nt = 0; nt < 4; nt++) gv[nt] = gamma[nt * 16 + l16];

#pragma unroll
  for (int mt = 0; mt < 4; mt++)
#pragma unroll
    for (int r = 0; r < 4; r++) {
      int row = m0 + wm + mt * 16 + quad * 4 + r;
      float ss = 0.f;
#pragma unroll
      for (int nt = 0; nt < 4; nt++) {
        float v = acc[mt][nt][r]; ss += v * v;
      }
#pragma unroll
      for (int off = 1; off < 16; off <<= 1) ss += __shfl_xor(ss, off);
      float rr = rsqrtf(ss * (1.0f / 64.0f) + 1e-6f);
      float xn[4];
#pragma unroll
      for (int nt = 0; nt < 4; nt++) xn[nt] = acc[mt][nt][r] * rr * gv[nt];
      int b = row >> 11, s = row & 2047;
      unsigned short* dst = (type == 0)
          ? Qn + ((size_t)(b * 32 + hb) * 2048 + s) * 64
          : Kn + ((size_t)(b * 4 + hb) * 2048 + s) * 64;
#pragma unroll
      for (int nt = 0; nt < 4; nt++) {
        int d = nt * 16 + l16;
        float rot = (nt < 2) ? -xn[nt ^ 2] : xn[nt ^ 2];
        float cv = cosb[(size_t)row * 64 + d];
        float sv = sinb[(size_t)row * 64 + d];
        dst[d] = f2bf((xn[nt] * cv + rot * sv) * scale);
      }
    }
}

// -------------------------------------------------------------- output GEMM
__global__ __launch_bounds__(512, 2) void gemm_out_k(
    const unsigned short* __restrict__ A, const unsigned short* __restrict__ W,
    float* __restrict__ C) {
  __shared__ __attribute__((aligned(16))) unsigned short lds[65536];  // 128 KB
  const int m0 = blockIdx.x * 128, n0 = blockIdx.y * 256;
  f32x4 acc[4][4];
  gemm_main_big(A, W, m0, n0, lds, acc);
  const int tid = threadIdx.x;
  const int w = tid >> 6, l = tid & 63, quad = l >> 4, l16 = l & 15;
  const int wm = (w & 1) * 64, wn = (w >> 1) * 64;
#pragma unroll
  for (int mt = 0; mt < 4; mt++)
#pragma unroll
    for (int nt = 0; nt < 4; nt++) {
      int row = m0 + wm + mt * 16 + quad * 4;
      int col = n0 + wn + nt * 16 + l16;
#pragma unroll
      for (int r = 0; r < 4; r++)
        C[(size_t)(row + r) * 2048 + col] = acc[mt][nt][r];
    }
}

// ---------------------------------------------------------- flash attention
// (unchanged from r6)
__global__ __launch_bounds__(256, 4) void attn(
    const unsigned short* __restrict__ Qn, const unsigned short* __restrict__ Kn,
    const unsigned short* __restrict__ Vt, const unsigned short* __restrict__ gate,
    unsigned short* __restrict__ act) {
  __shared__ __attribute__((aligned(16))) unsigned short smem[20480];  // 40 KB
  unsigned short* Ps = smem + 16384;    // 4 x [32 q][32 kv] = 8 KB

  const int tid = threadIdx.x, w = tid >> 6, l = tid & 63;
  const int quad = l >> 4, l16 = l & 15, l7 = l16 & 7;
  const int bh = blockIdx.y, b = bh >> 5, h = bh & 31, kvh = h >> 3;
  const int q0 = blockIdx.x * 128;

  const unsigned short* Qg = Qn + ((size_t)(b * 32 + h) * 2048 + q0) * 64;
  const unsigned short* Kg = Kn + (size_t)(b * 4 + kvh) * 2048 * 64;
  const unsigned short* Vg = Vt + (size_t)(b * 4 + kvh) * 64 * 2048;
  unsigned short* Pw = Ps + w * 1024;   // wave-private [32 q][32 kv]

  const int kq_src = ((tid & 7) ^ ((tid >> 3) & 7)) * 8;

  // ---- prologue: stage Q [128][64] into smem[0..8192), read q-fragments
#pragma unroll
  for (int i = 0; i < 4; i++)
    async16(smem + i * 2048 + tid * 8,
            Qg + (size_t)(i * 32 + (tid >> 3)) * 64 + kq_src);
  __syncthreads();
  bf16x8 qf[2][2];
#pragma unroll
  for (int mt = 0; mt < 2; mt++)
#pragma unroll
    for (int ks = 0; ks < 2; ks++) {
      int row = w * 32 + mt * 16 + l16;           // row&7 == l7
      qf[mt][ks] = *(const bf16x8*)&smem[row * 64 + ((ks * 4 + quad) ^ l7) * 8];
    }
  __syncthreads();   // Q region free for K/V staging

  const f32x4 Z4 = {0.f, 0.f, 0.f, 0.f};
  f32x4 O[2][4];
  float lp[2][4];
#pragma unroll
  for (int mt = 0; mt < 2; mt++) {
#pragma unroll
    for (int nt = 0; nt < 4; nt++) O[mt][nt] = Z4;
#pragma unroll
    for (int r = 0; r < 4; r++) lp[mt][r] = 0.f;
  }

  // stage tile 0 into buf0
#pragma unroll
  for (int i = 0; i < 2; i++) {
    async16(smem + i * 2048 + tid * 8,
            Kg + (size_t)(i * 32 + (tid >> 3)) * 64 + kq_src);
    async16(smem + 4096 + i * 2048 + tid * 8,
            Vg + (size_t)(i * 32 + (tid >> 3)) * 2048 + kq_src);
  }

  for (int kt = 0; kt < 32; kt++) {
    __syncthreads();   // drains stage(kt); all waves past compute(kt-1)

    if (kt < 31) {     // stage tile kt+1 into the other buffer (overlapped)
      unsigned short* nb = smem + ((kt + 1) & 1) * 8192;
      const int s1 = (kt + 1) * 64;
#pragma unroll
      for (int i = 0; i < 2; i++) {
        async16(nb + i * 2048 + tid * 8,
                Kg + (size_t)(s1 + i * 32 + (tid >> 3)) * 64 + kq_src);
        async16(nb + 4096 + i * 2048 + tid * 8,
                Vg + (size_t)(i * 32 + (tid >> 3)) * 2048 + s1 + kq_src);
      }
    }

    unsigned short* Ks  = smem + (kt & 1) * 8192;
    unsigned short* Vts = Ks + 4096;

    // ---- S = Q K^T over this kv-64 tile
    f32x4 sc[2][4];
#pragma unroll
    for (int mt = 0; mt < 2; mt++)
#pragma unroll
      for (int nt = 0; nt < 4; nt++) sc[mt][nt] = Z4;
#pragma unroll
    for (int nt = 0; nt < 4; nt++) {
      int row = nt * 16 + l16;                    // row&7 == l7
      bf16x8 kf0 = *(const bf16x8*)&Ks[row * 64 + (quad ^ l7) * 8];
      bf16x8 kf1 = *(const bf16x8*)&Ks[row * 64 + ((4 + quad) ^ l7) * 8];
#pragma unroll
      for (int mt = 0; mt < 2; mt++) {
        sc[mt][nt] = __builtin_amdgcn_mfma_f32_16x16x32_bf16(qf[mt][0], kf0, sc[mt][nt], 0, 0, 0);
        sc[mt][nt] = __builtin_amdgcn_mfma_f32_16x16x32_bf16(qf[mt][1], kf1, sc[mt][nt], 0, 0, 0);
      }
    }

    // ---- softmax + PV in two kv-32 sub-chunks through wave-private Ps
#pragma unroll
    for (int ks2 = 0; ks2 < 2; ks2++) {
#pragma unroll
      for (int mt = 0; mt < 2; mt++)
#pragma unroll
        for (int ntl = 0; ntl < 2; ntl++) {
          int nt = ks2 * 2 + ntl;
#pragma unroll
          for (int r = 0; r < 4; r++) {
            float p = __builtin_amdgcn_exp2f(sc[mt][nt][r]);
            union { float f; unsigned u; } x; x.f = p;
            union { unsigned u; float f; } t; t.u = x.u & 0xffff0000u;
            lp[mt][r] += t.f;
            int q = mt * 16 + quad * 4 + r;
            int c = ntl * 2 + (l16 >> 3);
            int phys = c ^ ((q >> 1) & 3);
            Pw[q * 32 + phys * 8 + l7] = (unsigned short)(x.u >> 16);
          }
        }
      lds_fence();   // P writes visible before reads (same wave)

      bf16x8 pf[2];
#pragma unroll
      for (int mt = 0; mt < 2; mt++) {
        int q = mt * 16 + l16;
        int phys = quad ^ ((l16 >> 1) & 3);
        pf[mt] = *(const bf16x8*)&Pw[q * 32 + phys * 8];
      }
#pragma unroll
      for (int nt2 = 0; nt2 < 4; nt2++) {
        int d = nt2 * 16 + l16;                   // d&7 == l7
        bf16x8 vf = *(const bf16x8*)&Vts[d * 64 + ((ks2 * 4 + quad) ^ l7) * 8];
#pragma unroll
        for (int mt = 0; mt < 2; mt++)
          O[mt][nt2] = __builtin_amdgcn_mfma_f32_16x16x32_bf16(
              pf[mt], vf, O[mt][nt2], 0, 0, 0);
      }
      lds_fence();   // sub-chunk reads retired before next sub-chunk writes
    }
  }

  // ---- final l reduction across the 16-lane column groups (once)
#pragma unroll
  for (int mt = 0; mt < 2; mt++)
#pragma unroll
    for (int r = 0; r < 4; r++) {
      float s = lp[mt][r];
#pragma unroll
      for (int off = 1; off < 16; off <<= 1) s += __shfl_xor(s, off);
      lp[mt][r] = s;
    }

  // ---- epilogue: O/l * sigmoid(gate) -> act[b][s][h*64+d]
#pragma unroll
  for (int mt = 0; mt < 2; mt++) {
    float inv[4];
#pragma unroll
    for (int r = 0; r < 4; r++) inv[r] = 1.0f / lp[mt][r];
#pragma unroll
    for (int nt = 0; nt < 4; nt++)
#pragma unroll
      for (int r = 0; r < 4; r++) {
        int srow = q0 + w * 32 + mt * 16 + quad * 4 + r;
        int col = h * 64 + nt * 16 + l16;
        size_t off = (size_t)(b * 2048 + srow) * 2048 + col;
        float g = bf2f(gate[off]);
        float sig = 1.0f / (1.0f + __builtin_amdgcn_exp2f(-g * LOG2E));
        act[off] = f2bf(O[mt][nt][r] * inv[r] * sig);
      }
  }
}

// ------------------------------------------------------------------ launcher
extern "C" void kernel_launch(void* const* d_in, const int* in_sizes, int n_in,
                              void* d_out, int out_size, void* d_ws, size_t ws_size,
                              hipStream_t stream) {
  const float* hid  = (const float*)d_in[0];
  const float* cosb = (const float*)d_in[1];
  const float* sinb = (const float*)d_in[2];
  const float* Wq   = (const float*)d_in[3];
  const float* Wk   = (const float*)d_in[4];
  const float* Wv   = (const float*)d_in[5];
  const float* Wg   = (const float*)d_in[6];
  const float* Wo   = (const float*)d_in[7];
  const float* qg   = (const float*)d_in[8];
  const float* kg   = (const float*)d_in[9];
  float* out = (float*)d_out;

  char* ws = (char*)d_ws;
  unsigned short* Xb   = (unsigned short*)(ws);              // 16,777,216 B
  unsigned short* WqB  = (unsigned short*)(ws + 16777216);   //  8,388,608
  unsigned short* WkB  = (unsigned short*)(ws + 25165824);   //  1,048,576
  unsigned short* WvB  = (unsigned short*)(ws + 26214400);   //  1,048,576
  unsigned short* WgB  = (unsigned short*)(ws + 27262976);   //  8,388,608
  unsigned short* WoB  = (unsigned short*)(ws + 35651584);   //  8,388,608
  unsigned short* gate = (unsigned short*)(ws + 44040192);   // 16,777,216
  unsigned short* Qn   = (unsigned short*)(ws + 60817408);   // 16,777,216
  unsigned short* Kn   = (unsigned short*)(ws + 77594624);   //  2,097,152
  unsigned short* Vt   = (unsigned short*)(ws + 79691776);   //  2,097,152
  // region reuse: act overlays WqB..WgB (18 MB, dead after gemm_qkvg)
  unsigned short* act = WqB;

  cvt_all<<<dim3(21504), dim3(256), 0, stream>>>(
      hid, Wq, Wk, Wv, Wg, Wo, Xb, WqB, WkB, WvB, WgB, WoB);

  gemm_qkvg<<<dim3(32, 18), dim3(512), 0, stream>>>(
      Xb, WqB, WkB, WvB, WgB, cosb, sinb, qg, kg, Qn, Kn, Vt, gate);

  attn<<<dim3(16, 64), dim3(256), 0, stream>>>(Qn, Kn, Vt, gate, act);

  gemm_out_k<<<dim3(32, 8), dim3(512), 0, stream>>>(act, WoB, out);
}